// Round 1
// baseline (689.680 us; speedup 1.0000x reference)
//
#include <hip/hip_runtime.h>

// Problem constants
#define BI   1152   // B*N = 32*36
#define NREG 36
#define NPAD 48
#define DD   2048
#define RR   512
#define KK   1024   // 2*R

typedef __bf16 bf16;
typedef __bf16 bf16x8 __attribute__((ext_vector_type(8)));
typedef __bf16 bf16x4 __attribute__((ext_vector_type(4)));
typedef float  f32x4  __attribute__((ext_vector_type(4)));

__device__ __forceinline__ void gl_lds16(const void* g, void* l) {
  __builtin_amdgcn_global_load_lds(
      (const __attribute__((address_space(1))) unsigned int*)g,
      (__attribute__((address_space(3))) unsigned int*)l, 16, 0, 0);
}

// ---------------- stage 1a: mm f32 -> bf16 (same layout) ----------------
__global__ void k_cvt_mm(const float4* __restrict__ in, bf16x4* __restrict__ out) {
  int i = blockIdx.x * 256 + threadIdx.x;   // 2304*256 = 589824 = BI*DD/4 exactly
  float4 v = in[i];
  bf16x4 o = {(bf16)v.x, (bf16)v.y, (bf16)v.z, (bf16)v.w};
  out[i] = o;
}

// ---------------- stage 1b: f32 [nr][nc] -> bf16 transposed out[c*ostride+roff+r] ----
__global__ void k_transpose(const float* __restrict__ in, bf16* __restrict__ out,
                            int nr, int nc, int ostride, int roff) {
  __shared__ float tile[32][33];
  int tx = threadIdx.x, ty = threadIdx.y;        // block (32,8)
  int c0 = blockIdx.x * 32, r0 = blockIdx.y * 32;
#pragma unroll
  for (int k = 0; k < 4; k++) {
    int r = r0 + ty + 8 * k;
    tile[ty + 8 * k][tx] = in[(long)r * nc + c0 + tx];
  }
  __syncthreads();
#pragma unroll
  for (int k = 0; k < 4; k++) {
    int c = c0 + ty + 8 * k;
    out[(long)c * ostride + roff + r0 + tx] = (bf16)tile[tx][ty + 8 * k];
  }
}

// ---------------- stage 2: uc/vc (K=4, fp32) ----------------
__global__ void k_uvcoord(const float* __restrict__ coords, const float* __restrict__ Uc,
                          const float* __restrict__ Vc, float* __restrict__ uc,
                          float* __restrict__ vc) {
  int g = blockIdx.x, t = threadIdx.x;
  float c0 = coords[g * 4 + 0], c1 = coords[g * 4 + 1];
  float c2 = coords[g * 4 + 2], c3 = coords[g * 4 + 3];
#pragma unroll
  for (int i = 0; i < 2; i++) {
    int r = t + i * 256;
    uc[g * RR + r] = c0 * Uc[r] + c1 * Uc[RR + r] + c2 * Uc[2 * RR + r] + c3 * Uc[3 * RR + r];
    vc[g * RR + r] = c0 * Vc[r] + c1 * Vc[RR + r] + c2 * Vc[2 * RR + r] + c3 * Vc[3 * RR + r];
  }
}

// ---------------- stage 3: uf/vf = mm @ U_feat / V_feat (MFMA bf16, fp32 out) -------
// A = mmb [BI][2048], Bop = UT/VT [512][2048] (row = r, contiguous k). Tile 64x64.
__launch_bounds__(256)
__global__ void k_gemm_uv(const bf16* __restrict__ mmb, const bf16* __restrict__ UT,
                          const bf16* __restrict__ VT, float* __restrict__ uf,
                          float* __restrict__ vf) {
  __shared__ bf16 As[2048];   // [q4][64][8]
  __shared__ bf16 Bs[2048];   // [q4][64][8]
  const bf16* Bmat = blockIdx.z ? VT : UT;
  float* out = blockIdx.z ? vf : uf;
  int n0 = blockIdx.x * 64, m0 = blockIdx.y * 64;
  int tid = threadIdx.x, wave = tid >> 6, lane = tid & 63;

  int idx = wave * 64 + lane;            // 0..255
  int q = idx >> 6, rowi = idx & 63;
  const bf16* gA = mmb + (long)(m0 + rowi) * 2048 + q * 8;
  const bf16* gB = Bmat + (long)(n0 + rowi) * 2048 + q * 8;
  bf16* lA = As + wave * 512;
  bf16* lB = Bs + wave * 512;

  f32x4 acc[4] = {};
  for (int k0 = 0; k0 < 2048; k0 += 32) {
    __syncthreads();
    gl_lds16(gA + k0, lA);
    gl_lds16(gB + k0, lB);
    __syncthreads();
    bf16x8 bfr = *(const bf16x8*)(Bs + (lane >> 4) * 512 + (wave * 16 + (lane & 15)) * 8);
#pragma unroll
    for (int mt = 0; mt < 4; mt++) {
      bf16x8 afr = *(const bf16x8*)(As + (lane >> 4) * 512 + (mt * 16 + (lane & 15)) * 8);
      acc[mt] = __builtin_amdgcn_mfma_f32_16x16x32_bf16(afr, bfr, acc[mt], 0, 0, 0);
    }
  }
  int col = n0 + wave * 16 + (lane & 15);
#pragma unroll
  for (int mt = 0; mt < 4; mt++)
#pragma unroll
    for (int r = 0; r < 4; r++) {
      int row = m0 + mt * 16 + (lane >> 4) * 4 + r;
      out[(long)row * RR + col] = acc[mt][r];
    }
}

// ---------------- stage 4: z[g][j][k] = relu(u[g,k]*v[b*36+j,k]) bf16, j>=36 -> 0 ----
__global__ void k_build_z(const float* __restrict__ uc, const float* __restrict__ vc,
                          const float* __restrict__ uf, const float* __restrict__ vf,
                          bf16* __restrict__ z) {
  int j = blockIdx.x, g = blockIdx.y, t = threadIdx.x;
  bf16x4* zrow = (bf16x4*)(z + ((long)g * NPAD + j) * KK);
  if (j >= NREG) { bf16x4 zz = {(bf16)0.f, (bf16)0.f, (bf16)0.f, (bf16)0.f}; zrow[t] = zz; return; }
  int b = g / NREG;
  int vr = b * NREG + j;
  float4 u4, v4;
  if (t < 128) {
    u4 = *(const float4*)(uc + g * RR + 4 * t);
    v4 = *(const float4*)(vc + vr * RR + 4 * t);
  } else {
    u4 = *(const float4*)(uf + g * RR + 4 * t - RR);
    v4 = *(const float4*)(vf + vr * RR + 4 * t - RR);
  }
  float x0 = fmaxf(u4.x * v4.x, 0.f), x1 = fmaxf(u4.y * v4.y, 0.f);
  float x2 = fmaxf(u4.z * v4.z, 0.f), x3 = fmaxf(u4.w * v4.w, 0.f);
  bf16x4 o = {(bf16)x0, (bf16)x1, (bf16)x2, (bf16)x3};
  zrow[t] = o;
}

// ---------------- stage 5: main fused GEMM + masked max + residual ----------------
// Block: M=96 (2 bi x 48 rows) x N=256 d-cols, K=1024 in chunks of 32.
// LDS A [q4][128][8] (rows 96..127 clamped dup), B [q4][256][8].
__launch_bounds__(256, 2)
__global__ void k_main(const bf16* __restrict__ z, const bf16* __restrict__ PT,
                       const float* __restrict__ mm, float* __restrict__ out) {
  __shared__ bf16 As[4096];   // 8 KB
  __shared__ bf16 Bs[8192];   // 16 KB
  int g = blockIdx.y;          // bi pair: bi = 2g, 2g+1
  int d0 = blockIdx.x * 256;
  int tid = threadIdx.x, wave = tid >> 6, lane = tid & 63;

  // precompute staging: 24 segs of 1KB, seg s = wave + 4t
  const bf16* gp[6];
  bf16* lp[6];
#pragma unroll
  for (int t = 0; t < 6; t++) {
    int s = wave + 4 * t;
    if (s < 8) {             // A segs
      int idx = s * 64 + lane;           // 0..511
      int q = idx >> 7, m = idx & 127;
      int mc = m > 95 ? 95 : m;
      int half = (mc >= 48) ? 1 : 0;
      int row = mc - 48 * half;
      gp[t] = z + ((long)(g * 2 + half) * NPAD + row) * KK + q * 8;
      lp[t] = As + s * 512;
    } else {                 // B segs
      int idx = (s - 8) * 64 + lane;     // 0..1023
      int q = idx >> 8, n = idx & 255;
      gp[t] = PT + (long)(d0 + n) * KK + q * 8;
      lp[t] = Bs + (s - 8) * 512;
    }
  }

  f32x4 acc[6][4] = {};
  for (int k0 = 0; k0 < KK; k0 += 32) {
    __syncthreads();
#pragma unroll
    for (int t = 0; t < 6; t++) gl_lds16(gp[t] + k0, lp[t]);
    __syncthreads();
    bf16x8 a[6], b[4];
#pragma unroll
    for (int mt = 0; mt < 6; mt++)
      a[mt] = *(const bf16x8*)(As + (lane >> 4) * 1024 + (mt * 16 + (lane & 15)) * 8);
#pragma unroll
    for (int nt = 0; nt < 4; nt++)
      b[nt] = *(const bf16x8*)(Bs + (lane >> 4) * 2048 + (wave * 64 + nt * 16 + (lane & 15)) * 8);
#pragma unroll
    for (int mt = 0; mt < 6; mt++)
#pragma unroll
      for (int nt = 0; nt < 4; nt++)
        acc[mt][nt] = __builtin_amdgcn_mfma_f32_16x16x32_bf16(a[mt], b[nt], acc[mt][nt], 0, 0, 0);
  }

  // epilogue: per bi-half, masked max over rows (j), then + mm residual
#pragma unroll
  for (int half = 0; half < 2; half++) {
    int bi = g * 2 + half;
#pragma unroll
    for (int nt = 0; nt < 4; nt++) {
      float m1 = -3.0e38f;
#pragma unroll
      for (int mt3 = 0; mt3 < 3; mt3++) {
        int mt = half * 3 + mt3;
#pragma unroll
        for (int r = 0; r < 4; r++) {
          int row = mt3 * 16 + (lane >> 4) * 4 + r;   // row within bi, 0..47
          float v = acc[mt][nt][r];
          if (row < NREG) m1 = fmaxf(m1, v);
        }
      }
      m1 = fmaxf(m1, __shfl_xor(m1, 16, 64));
      m1 = fmaxf(m1, __shfl_xor(m1, 32, 64));
      if (lane < 16) {
        int d = d0 + wave * 64 + nt * 16 + lane;
        out[(long)bi * DD + d] = m1 + mm[(long)bi * DD + d];
      }
    }
  }
}

// ---------------- launcher ----------------
extern "C" void kernel_launch(void* const* d_in, const int* in_sizes, int n_in,
                              void* d_out, int out_size, void* d_ws, size_t ws_size,
                              hipStream_t stream) {
  const float* mm     = (const float*)d_in[0];
  const float* coords = (const float*)d_in[1];
  const float* U_feat = (const float*)d_in[2];
  const float* V_feat = (const float*)d_in[3];
  const float* P_feat = (const float*)d_in[4];
  const float* U_coord= (const float*)d_in[5];
  const float* V_coord= (const float*)d_in[6];
  const float* P_coord= (const float*)d_in[7];
  float* out = (float*)d_out;

  char* ws = (char*)d_ws;
  bf16* z   = (bf16*)(ws + 0);                 // 113246208 B
  bf16* PT  = (bf16*)(ws + 113246208);         //   4194304 B
  bf16* mmb = (bf16*)(ws + 117440512);         //   4718592 B
  bf16* UT  = (bf16*)(ws + 122159104);         //   2097152 B
  bf16* VT  = (bf16*)(ws + 124256256);         //   2097152 B
  float* uf = (float*)(ws + 126353408);        //   2359296 B
  float* vf = (float*)(ws + 128712704);
  float* uc = (float*)(ws + 131072000);
  float* vc = (float*)(ws + 133431296);        // end 135790592

  // stage 1: conversions / transposes
  k_cvt_mm<<<dim3(2304), dim3(256), 0, stream>>>((const float4*)mm, (bf16x4*)mmb);
  k_transpose<<<dim3(16, 64), dim3(32, 8), 0, stream>>>(U_feat, UT, 2048, 512, 2048, 0);
  k_transpose<<<dim3(16, 64), dim3(32, 8), 0, stream>>>(V_feat, VT, 2048, 512, 2048, 0);
  k_transpose<<<dim3(64, 16), dim3(32, 8), 0, stream>>>(P_coord, PT, 512, 2048, 1024, 0);
  k_transpose<<<dim3(64, 16), dim3(32, 8), 0, stream>>>(P_feat,  PT, 512, 2048, 1024, 512);
  // stage 2: coord projections
  k_uvcoord<<<dim3(BI), dim3(256), 0, stream>>>(coords, U_coord, V_coord, uc, vc);
  // stage 3: feature projections
  k_gemm_uv<<<dim3(8, 18, 2), dim3(256), 0, stream>>>(mmb, UT, VT, uf, vf);
  // stage 4: z
  k_build_z<<<dim3(NPAD, BI), dim3(256), 0, stream>>>(uc, vc, uf, vf, z);
  // stage 5: fused GEMM + max + residual
  k_main<<<dim3(8, BI / 2), dim3(256), 0, stream>>>(z, PT, mm, out);
}

// Round 2
// 349.083 us; speedup vs baseline: 1.9757x; 1.9757x over previous
//
#include <hip/hip_runtime.h>

// Problem constants
#define BI    1152   // B*N = 32*36
#define NREG  36
#define DD    2048
#define RR    512
#define KK    1024   // 2*R
#define ZROWS (BI*NREG)        // 41472
#define MBLK  144              // 4 bi * 36 rows, exact
#define NBLK  128
#define ABUF  4608             // 144*32 bf16 elems (9 KB)
#define BBUF  4096             // 128*32 bf16 elems (8 KB)
#define BUFE  (ABUF+BBUF)      // 8704 elems = 17 KB per buffer

typedef __bf16 bf16;
typedef __bf16 bf16x8 __attribute__((ext_vector_type(8)));
typedef __bf16 bf16x4 __attribute__((ext_vector_type(4)));
typedef float  f32x4  __attribute__((ext_vector_type(4)));

__device__ __forceinline__ void gl_lds16(const void* g, void* l) {
  __builtin_amdgcn_global_load_lds(
      (const __attribute__((address_space(1))) unsigned int*)g,
      (__attribute__((address_space(3))) unsigned int*)l, 16, 0, 0);
}

// ---------------- stage 1a: mm f32 -> bf16 (same layout) ----------------
__global__ void k_cvt_mm(const float4* __restrict__ in, bf16x4* __restrict__ out) {
  int i = blockIdx.x * 256 + threadIdx.x;   // 2304*256 = BI*DD/4 exactly
  float4 v = in[i];
  bf16x4 o = {(bf16)v.x, (bf16)v.y, (bf16)v.z, (bf16)v.w};
  out[i] = o;
}

// ------- stage 1b: U/V_feat f32 [2048][512] -> bf16 UT/VT [512 r][2048 k] -------
__global__ void k_transpose(const float* __restrict__ in, bf16* __restrict__ out,
                            int nc, int ostride) {
  __shared__ float tile[32][33];
  int tx = threadIdx.x, ty = threadIdx.y;        // block (32,8)
  int c0 = blockIdx.x * 32, r0 = blockIdx.y * 32;
#pragma unroll
  for (int k = 0; k < 4; k++)
    tile[ty + 8 * k][tx] = in[(long)(r0 + ty + 8 * k) * nc + c0 + tx];
  __syncthreads();
#pragma unroll
  for (int k = 0; k < 4; k++)
    out[(long)(c0 + ty + 8 * k) * ostride + r0 + tx] = (bf16)tile[tx][ty + 8 * k];
}

// ------- stage 1c: P_* f32 [512 r][2048 d] -> PT_t [kc][2048][32] bf16 -------
__global__ void k_transpose_pt(const float* __restrict__ in, bf16* __restrict__ out,
                               int koff) {
  __shared__ float tile[32][33];
  int tx = threadIdx.x, ty = threadIdx.y;        // block (32,8)
  int c0 = blockIdx.x * 32, r0 = blockIdx.y * 32;
#pragma unroll
  for (int k = 0; k < 4; k++)
    tile[ty + 8 * k][tx] = in[(long)(r0 + ty + 8 * k) * 2048 + c0 + tx];
  __syncthreads();
  int kc = (koff + r0) >> 5;                     // r0 32-aligned
#pragma unroll
  for (int k = 0; k < 4; k++) {
    int d = c0 + ty + 8 * k;
    out[((long)kc * 2048 + d) * 32 + tx] = (bf16)tile[tx][ty + 8 * k];
  }
}

// ---------------- stage 2: uc/vc (K=4, fp32) ----------------
__global__ void k_uvcoord(const float* __restrict__ coords, const float* __restrict__ Uc,
                          const float* __restrict__ Vc, float* __restrict__ uc,
                          float* __restrict__ vc) {
  int g = blockIdx.x, t = threadIdx.x;
  float c0 = coords[g * 4 + 0], c1 = coords[g * 4 + 1];
  float c2 = coords[g * 4 + 2], c3 = coords[g * 4 + 3];
#pragma unroll
  for (int i = 0; i < 2; i++) {
    int r = t + i * 256;
    uc[g * RR + r] = c0 * Uc[r] + c1 * Uc[RR + r] + c2 * Uc[2 * RR + r] + c3 * Uc[3 * RR + r];
    vc[g * RR + r] = c0 * Vc[r] + c1 * Vc[RR + r] + c2 * Vc[2 * RR + r] + c3 * Vc[3 * RR + r];
  }
}

// ---------------- stage 3: uf/vf = mm @ U_feat / V_feat (MFMA bf16) -------
__launch_bounds__(256)
__global__ void k_gemm_uv(const bf16* __restrict__ mmb, const bf16* __restrict__ UT,
                          const bf16* __restrict__ VT, float* __restrict__ uf,
                          float* __restrict__ vf) {
  __shared__ bf16 As[2048];
  __shared__ bf16 Bs[2048];
  const bf16* Bmat = blockIdx.z ? VT : UT;
  float* out = blockIdx.z ? vf : uf;
  int n0 = blockIdx.x * 64, m0 = blockIdx.y * 64;
  int tid = threadIdx.x, wave = tid >> 6, lane = tid & 63;

  int idx = wave * 64 + lane;
  int q = idx >> 6, rowi = idx & 63;
  const bf16* gA = mmb + (long)(m0 + rowi) * 2048 + q * 8;
  const bf16* gB = Bmat + (long)(n0 + rowi) * 2048 + q * 8;
  bf16* lA = As + wave * 512;
  bf16* lB = Bs + wave * 512;

  f32x4 acc[4] = {};
  for (int k0 = 0; k0 < 2048; k0 += 32) {
    __syncthreads();
    gl_lds16(gA + k0, lA);
    gl_lds16(gB + k0, lB);
    __syncthreads();
    bf16x8 bfr = *(const bf16x8*)(Bs + (lane >> 4) * 512 + (wave * 16 + (lane & 15)) * 8);
#pragma unroll
    for (int mt = 0; mt < 4; mt++) {
      bf16x8 afr = *(const bf16x8*)(As + (lane >> 4) * 512 + (mt * 16 + (lane & 15)) * 8);
      acc[mt] = __builtin_amdgcn_mfma_f32_16x16x32_bf16(afr, bfr, acc[mt], 0, 0, 0);
    }
  }
  int col = n0 + wave * 16 + (lane & 15);
#pragma unroll
  for (int mt = 0; mt < 4; mt++)
#pragma unroll
    for (int r = 0; r < 4; r++) {
      int row = m0 + mt * 16 + (lane >> 4) * 4 + r;
      out[(long)row * RR + col] = acc[mt][r];
    }
}

// ------- stage 4: z_t[kc][row][32] = relu(u[g,k]*v[b*36+j,k]) bf16, row=g*36+j -------
__global__ void k_build_z(const float* __restrict__ uc, const float* __restrict__ vc,
                          const float* __restrict__ uf, const float* __restrict__ vf,
                          bf16* __restrict__ z) {
  int j = blockIdx.x, g = blockIdx.y, t = threadIdx.x;
  int row = g * NREG + j;
  int b = g / NREG;
  int vr = b * NREG + j;
  float4 u4, v4;
  if (t < 128) {
    u4 = *(const float4*)(uc + g * RR + 4 * t);
    v4 = *(const float4*)(vc + vr * RR + 4 * t);
  } else {
    u4 = *(const float4*)(uf + g * RR + 4 * t - RR);
    v4 = *(const float4*)(vf + vr * RR + 4 * t - RR);
  }
  float x0 = fmaxf(u4.x * v4.x, 0.f), x1 = fmaxf(u4.y * v4.y, 0.f);
  float x2 = fmaxf(u4.z * v4.z, 0.f), x3 = fmaxf(u4.w * v4.w, 0.f);
  bf16x4 o = {(bf16)x0, (bf16)x1, (bf16)x2, (bf16)x3};
  int kc = t >> 3, kk = (t & 7) * 4;
  *(bf16x4*)(z + ((long)kc * ZROWS + row) * 32 + kk) = o;
}

// ---------------- stage 5: main fused GEMM + masked max + residual ----------------
// Block: M=144 (4 bi x 36 exact) x N=128, BK=32, double-buffered LDS (2x17KB).
// z layout [kc][row][32], PT_t layout [kc][d][32]: per-k-step tiles are contiguous.
// k-quad XOR swizzle (on global source addr) keeps ds_read_b128 conflict-free.
__launch_bounds__(256, 2)
__global__ void k_main(const bf16* __restrict__ z, const bf16* __restrict__ PTt,
                       const float* __restrict__ mm, float* __restrict__ out) {
  __shared__ bf16 lds[2 * BUFE];   // 34 KB
  int bid = blockIdx.x;
  // XCD swizzle: all 16 d-tiles of one g-quad land on the same XCD (bid%8) within
  // a 128-id window -> z tile becomes an L2 hit after first toucher.
  int x = bid & 7, dt = (bid >> 3) & 15, chunk = bid >> 7;  // chunk 0..35
  int gq = chunk * 8 + x;                                    // 0..287
  int d0 = dt * NBLK;
  int tid = threadIdx.x, wave = tid >> 6, lane = tid & 63;
  int l15 = lane & 15, qv = lane >> 4;
  int qp_c = qv ^ ((l15 >> 1) & 3);        // compute-side swizzled k-quad

  // staging: 17 segs of 1 KB (A: 0..8, B: 9..16); wave w takes segs w, w+4, ...
  // within a seg: idx = s*64+lane, row = idx>>2, store-order quad qp = idx&3,
  // global quad q = qp ^ ((row>>1)&3)  ->  q = (lane&3) ^ ((lane>>3)&3).
  const bf16* gp[5];
  int lofs[5];
  long kst[5];
  int qs = (lane & 3) ^ ((lane >> 3) & 3);
  int lroff = (lane >> 2) * 32 + qs * 8;   // within-seg global elem offset
#pragma unroll
  for (int i = 0; i < 5; i++) {
    int s = wave + 4 * i;
    if (s < 9) {
      gp[i] = z + (long)gq * (MBLK * 32) + s * 512 + lroff;
      lofs[i] = s * 512;
      kst[i] = (long)ZROWS * 32;
    } else if (s < 17) {
      int sb = s - 9;
      gp[i] = PTt + (long)d0 * 32 + sb * 512 + lroff;
      lofs[i] = ABUF + sb * 512;
      kst[i] = 2048L * 32;
    }
  }

  auto stage = [&](int buf) {
#pragma unroll
    for (int i = 0; i < 5; i++) {
      int s = wave + 4 * i;
      if (s < 17) {
        gl_lds16(gp[i], lds + buf * BUFE + lofs[i]);
        gp[i] += kst[i];
      }
    }
  };

  f32x4 acc[9][2] = {};
  stage(0);
  for (int kc = 0; kc < 32; kc++) {
    __syncthreads();                 // drains vmcnt for buf[kc&1] (issued 1 iter ago)
    if (kc < 31) stage((kc + 1) & 1);   // in flight during this iter's compute
    const bf16* cur = lds + (kc & 1) * BUFE;
    bf16x8 a[9], b[2];
#pragma unroll
    for (int mt = 0; mt < 9; mt++)
      a[mt] = *(const bf16x8*)(cur + mt * 512 + l15 * 32 + qp_c * 8);
#pragma unroll
    for (int nt = 0; nt < 2; nt++)
      b[nt] = *(const bf16x8*)(cur + ABUF + wave * 1024 + nt * 512 + l15 * 32 + qp_c * 8);
#pragma unroll
    for (int mt = 0; mt < 9; mt++)
#pragma unroll
      for (int nt = 0; nt < 2; nt++)
        acc[mt][nt] = __builtin_amdgcn_mfma_f32_16x16x32_bf16(a[mt], b[nt], acc[mt][nt], 0, 0, 0);
  }

  // epilogue: max over j (36 rows per bi, 4 bi per block), + residual
#pragma unroll
  for (int nt = 0; nt < 2; nt++) {
#pragma unroll
    for (int h = 0; h < 4; h++) {
      float m1 = -3.0e38f;
#pragma unroll
      for (int mt = 0; mt < 9; mt++)
#pragma unroll
        for (int r = 0; r < 4; r++) {
          int row = mt * 16 + qv * 4 + r;
          if (row >= h * NREG && row < h * NREG + NREG) m1 = fmaxf(m1, acc[mt][nt][r]);
        }
      m1 = fmaxf(m1, __shfl_xor(m1, 16, 64));
      m1 = fmaxf(m1, __shfl_xor(m1, 32, 64));
      if (lane < 16) {
        long o = (long)(gq * 4 + h) * DD + d0 + wave * 32 + nt * 16 + lane;
        out[o] = m1 + mm[o];
      }
    }
  }
}

// ---------------- launcher ----------------
extern "C" void kernel_launch(void* const* d_in, const int* in_sizes, int n_in,
                              void* d_out, int out_size, void* d_ws, size_t ws_size,
                              hipStream_t stream) {
  const float* mm     = (const float*)d_in[0];
  const float* coords = (const float*)d_in[1];
  const float* U_feat = (const float*)d_in[2];
  const float* V_feat = (const float*)d_in[3];
  const float* P_feat = (const float*)d_in[4];
  const float* U_coord= (const float*)d_in[5];
  const float* V_coord= (const float*)d_in[6];
  const float* P_coord= (const float*)d_in[7];
  float* out = (float*)d_out;

  char* ws = (char*)d_ws;
  bf16* z   = (bf16*)(ws + 0);                 //  84,934,656 B  [kc][41472][32]
  bf16* PTt = (bf16*)(ws + 84934656);          //   4,194,304 B  [kc][2048][32]
  bf16* mmb = (bf16*)(ws + 89128960);          //   4,718,592 B
  bf16* UT  = (bf16*)(ws + 93847552);          //   2,097,152 B  [512][2048]
  bf16* VT  = (bf16*)(ws + 95944704);          //   2,097,152 B
  float* uf = (float*)(ws + 98041856);         //   2,359,296 B
  float* vf = (float*)(ws + 100401152);
  float* uc = (float*)(ws + 102760448);
  float* vc = (float*)(ws + 105119744);        // end 107,479,040

  k_cvt_mm<<<dim3(2304), dim3(256), 0, stream>>>((const float4*)mm, (bf16x4*)mmb);
  k_transpose<<<dim3(16, 64), dim3(32, 8), 0, stream>>>(U_feat, UT, 512, 2048);
  k_transpose<<<dim3(16, 64), dim3(32, 8), 0, stream>>>(V_feat, VT, 512, 2048);
  k_transpose_pt<<<dim3(64, 16), dim3(32, 8), 0, stream>>>(P_coord, PTt, 0);
  k_transpose_pt<<<dim3(64, 16), dim3(32, 8), 0, stream>>>(P_feat,  PTt, 512);
  k_uvcoord<<<dim3(BI), dim3(256), 0, stream>>>(coords, U_coord, V_coord, uc, vc);
  k_gemm_uv<<<dim3(8, 18, 2), dim3(256), 0, stream>>>(mmb, UT, VT, uf, vf);
  k_build_z<<<dim3(NREG, BI), dim3(256), 0, stream>>>(uc, vc, uf, vf, z);
  k_main<<<dim3(4608), dim3(256), 0, stream>>>(z, PTt, mm, out);
}

// Round 3
// 288.005 us; speedup vs baseline: 2.3947x; 1.2121x over previous
//
#include <hip/hip_runtime.h>

// Problem constants
#define BI    1152   // B*N = 32*36
#define NREG  36
#define DD    2048
#define RR    512
#define KK    1024   // 2*R
#define ZROWS (BI*NREG)        // 41472
#define MBLK  288              // 8 bi * 36 rows = 18*16, exact both ways
#define NBLK  128
#define ABUF  (MBLK*32)        // 9216 elems (18 KB)
#define BBUF  (NBLK*32)        // 4096 elems (8 KB)
#define BUFE  (ABUF+BBUF)      // 13312 elems = 26 KB per buffer

typedef __bf16 bf16;
typedef __bf16 bf16x8 __attribute__((ext_vector_type(8)));
typedef __bf16 bf16x4 __attribute__((ext_vector_type(4)));
typedef float  f32x4  __attribute__((ext_vector_type(4)));

__device__ __forceinline__ void gl_lds16(const void* g, void* l) {
  __builtin_amdgcn_global_load_lds(
      (const __attribute__((address_space(1))) unsigned int*)g,
      (__attribute__((address_space(3))) unsigned int*)l, 16, 0, 0);
}

// ---------------- stage 1a: mm f32 -> bf16 (same layout) ----------------
__global__ void k_cvt_mm(const float4* __restrict__ in, bf16x4* __restrict__ out) {
  int i = blockIdx.x * 256 + threadIdx.x;   // 2304*256 = BI*DD/4 exactly
  float4 v = in[i];
  bf16x4 o = {(bf16)v.x, (bf16)v.y, (bf16)v.z, (bf16)v.w};
  out[i] = o;
}

// ------- stage 1b: U/V_feat f32 [2048][512] -> bf16 UT/VT [512 r][2048 k] -------
__global__ void k_transpose_uv(const float* __restrict__ U, const float* __restrict__ V,
                               bf16* __restrict__ UT, bf16* __restrict__ VT) {
  __shared__ float tile[32][33];
  const float* in = blockIdx.z ? V : U;
  bf16* out = blockIdx.z ? VT : UT;
  int tx = threadIdx.x, ty = threadIdx.y;        // block (32,8)
  int c0 = blockIdx.x * 32, r0 = blockIdx.y * 32;
#pragma unroll
  for (int k = 0; k < 4; k++)
    tile[ty + 8 * k][tx] = in[(long)(r0 + ty + 8 * k) * 512 + c0 + tx];
  __syncthreads();
#pragma unroll
  for (int k = 0; k < 4; k++)
    out[(long)(c0 + ty + 8 * k) * 2048 + r0 + tx] = (bf16)tile[tx][ty + 8 * k];
}

// ------- stage 1c: P_* f32 [512 r][2048 d] -> PT_t [kc][2048][32] bf16 -------
__global__ void k_transpose_pt(const float* __restrict__ Pc, const float* __restrict__ Pf,
                               bf16* __restrict__ out) {
  __shared__ float tile[32][33];
  const float* in = blockIdx.z ? Pf : Pc;
  int koff = blockIdx.z * 512;
  int tx = threadIdx.x, ty = threadIdx.y;        // block (32,8)
  int c0 = blockIdx.x * 32, r0 = blockIdx.y * 32;
#pragma unroll
  for (int k = 0; k < 4; k++)
    tile[ty + 8 * k][tx] = in[(long)(r0 + ty + 8 * k) * 2048 + c0 + tx];
  __syncthreads();
  int kc = (koff + r0) >> 5;
#pragma unroll
  for (int k = 0; k < 4; k++) {
    int d = c0 + ty + 8 * k;
    out[((long)kc * 2048 + d) * 32 + tx] = (bf16)tile[tx][ty + 8 * k];
  }
}

// ---------------- stage 2: uc/vc (K=4, fp32) ----------------
__global__ void k_uvcoord(const float* __restrict__ coords, const float* __restrict__ Uc,
                          const float* __restrict__ Vc, float* __restrict__ uc,
                          float* __restrict__ vc) {
  int g = blockIdx.x, t = threadIdx.x;
  float c0 = coords[g * 4 + 0], c1 = coords[g * 4 + 1];
  float c2 = coords[g * 4 + 2], c3 = coords[g * 4 + 3];
#pragma unroll
  for (int i = 0; i < 2; i++) {
    int r = t + i * 256;
    uc[g * RR + r] = c0 * Uc[r] + c1 * Uc[RR + r] + c2 * Uc[2 * RR + r] + c3 * Uc[3 * RR + r];
    vc[g * RR + r] = c0 * Vc[r] + c1 * Vc[RR + r] + c2 * Vc[2 * RR + r] + c3 * Vc[3 * RR + r];
  }
}

// ---------------- stage 3: uf/vf = mm @ U_feat / V_feat (MFMA bf16, dbuf) -------
__launch_bounds__(256)
__global__ void k_gemm_uv(const bf16* __restrict__ mmb, const bf16* __restrict__ UT,
                          const bf16* __restrict__ VT, float* __restrict__ uf,
                          float* __restrict__ vf) {
  __shared__ bf16 As[2][2048];
  __shared__ bf16 Bs[2][2048];
  const bf16* Bmat = blockIdx.z ? VT : UT;
  float* out = blockIdx.z ? vf : uf;
  int n0 = blockIdx.x * 64, m0 = blockIdx.y * 64;
  int tid = threadIdx.x, wave = tid >> 6, lane = tid & 63;

  const bf16* gA = mmb + (long)(m0 + lane) * 2048 + wave * 8;
  const bf16* gB = Bmat + (long)(n0 + lane) * 2048 + wave * 8;

  f32x4 acc[4] = {};
  gl_lds16(gA, As[0] + wave * 512);
  gl_lds16(gB, Bs[0] + wave * 512);
  for (int k0 = 0; k0 < 2048; k0 += 32) {
    int cur = (k0 >> 5) & 1;
    __syncthreads();
    if (k0 + 32 < 2048) {
      gl_lds16(gA + k0 + 32, As[cur ^ 1] + wave * 512);
      gl_lds16(gB + k0 + 32, Bs[cur ^ 1] + wave * 512);
    }
    bf16x8 bfr = *(const bf16x8*)(Bs[cur] + (lane >> 4) * 512 + (wave * 16 + (lane & 15)) * 8);
#pragma unroll
    for (int mt = 0; mt < 4; mt++) {
      bf16x8 afr = *(const bf16x8*)(As[cur] + (lane >> 4) * 512 + (mt * 16 + (lane & 15)) * 8);
      acc[mt] = __builtin_amdgcn_mfma_f32_16x16x32_bf16(afr, bfr, acc[mt], 0, 0, 0);
    }
  }
  int col = n0 + wave * 16 + (lane & 15);
#pragma unroll
  for (int mt = 0; mt < 4; mt++)
#pragma unroll
    for (int r = 0; r < 4; r++) {
      int row = m0 + mt * 16 + (lane >> 4) * 4 + r;
      out[(long)row * RR + col] = acc[mt][r];
    }
}

// ------- stage 4: z_t[kc][row][32] = relu(u[g,k]*v[b*36+j,k]) bf16 -------
// Block = (k-chunk of 128, batch b). u/v slices staged in LDS once; writes contiguous.
__global__ void k_build_z(const float* __restrict__ uc, const float* __restrict__ vc,
                          const float* __restrict__ uf, const float* __restrict__ vf,
                          bf16* __restrict__ z) {
  __shared__ float uL[36 * 128];
  __shared__ float vL[36 * 128];
  int kq = blockIdx.x, b = blockIdx.y, tid = threadIdx.x;
  const float* usrc = (kq < 4) ? uc : uf;
  const float* vsrc = (kq < 4) ? vc : vf;
  int kb = (kq & 3) * 128;
  // load 36x128 f32 slices (1152 float4 each)
  for (int i = tid; i < 1152; i += 256) {
    int row = i >> 5, kk = (i & 31) * 4;
    long src = (long)(b * 36 + row) * RR + kb + kk;
    *(float4*)&uL[row * 128 + kk] = *(const float4*)(usrc + src);
    *(float4*)&vL[row * 128 + kk] = *(const float4*)(vsrc + src);
  }
  __syncthreads();
  // write z slice: [4 kc][1296 rows][32], as bf16x4 chunks: 41472 chunks
  for (int c = tid; c < 41472; c += 256) {
    int kcl = c / 10368;            // 1296*8
    int rem = c - kcl * 10368;
    int row = rem >> 3;             // 0..1295 = g_local*36 + j
    int x4 = rem & 7;
    int gl = row / 36;
    int j = row - gl * 36;
    int kl = kcl * 32 + x4 * 4;
    float4 u4 = *(const float4*)&uL[gl * 128 + kl];
    float4 v4 = *(const float4*)&vL[j * 128 + kl];
    float x0 = fmaxf(u4.x * v4.x, 0.f), x1 = fmaxf(u4.y * v4.y, 0.f);
    float x2 = fmaxf(u4.z * v4.z, 0.f), x3 = fmaxf(u4.w * v4.w, 0.f);
    bf16x4 o = {(bf16)x0, (bf16)x1, (bf16)x2, (bf16)x3};
    *(bf16x4*)(z + ((long)(kq * 4 + kcl) * ZROWS + (long)b * 1296 + row) * 32 + x4 * 4) = o;
  }
}

// ---------------- stage 5: main fused GEMM + masked max + residual ----------------
// Block: M=288 (8 bi) x N=128, 4 waves as 2x2 (wave = 144 rows x 64 cols),
// BK=32, double-buffered LDS (2x26KB), stage-ahead, XOR k-quad swizzle.
__launch_bounds__(256, 2)
__global__ void k_main(const bf16* __restrict__ z, const bf16* __restrict__ PTt,
                       const float* __restrict__ mm, float* __restrict__ out) {
  __shared__ bf16 lds[2 * BUFE];   // 52 KB
  int bid = blockIdx.x;
  // XCD swizzle: 16 d-tiles of one go land on the same XCD within a 128-id window.
  int x = bid & 7, dt = (bid >> 3) & 15, chunk = bid >> 7;  // chunk 0..17
  int go = chunk * 8 + x;                                    // 0..143 (8-bi groups)
  int d0 = dt * NBLK;
  int tid = threadIdx.x, wave = tid >> 6, lane = tid & 63;
  int l15 = lane & 15, qv = lane >> 4;
  int qp_c = qv ^ ((l15 >> 1) & 3);
  int mstrip = (wave >> 1) * 144;
  int nstrip = (wave & 1) * 64;

  // staging: 26 segs of 1 KB (A: 0..17, B: 18..25); wave w takes segs w, w+4, ...
  const bf16* gp[7];
  int lofs[7];
  long kst[7];
  int qs = (lane & 3) ^ ((lane >> 3) & 3);
  int lroff = (lane >> 2) * 32 + qs * 8;
#pragma unroll
  for (int i = 0; i < 7; i++) {
    int s = wave + 4 * i;
    if (s < 18) {
      gp[i] = z + (long)go * (MBLK * 32) + s * 512 + lroff;
      lofs[i] = s * 512;
      kst[i] = (long)ZROWS * 32;
    } else if (s < 26) {
      int sb = s - 18;
      gp[i] = PTt + (long)d0 * 32 + sb * 512 + lroff;
      lofs[i] = ABUF + sb * 512;
      kst[i] = 2048L * 32;
    }
  }

  auto stage = [&](int buf) {
#pragma unroll
    for (int i = 0; i < 7; i++) {
      int s = wave + 4 * i;
      if (s < 26) {
        gl_lds16(gp[i], lds + buf * BUFE + lofs[i]);
        gp[i] += kst[i];
      }
    }
  };

  f32x4 acc[9][4] = {};
  stage(0);
  for (int kc = 0; kc < 32; kc++) {
    __syncthreads();
    if (kc < 31) stage((kc + 1) & 1);
    const bf16* cur = lds + (kc & 1) * BUFE;
    bf16x8 a[9], b[4];
#pragma unroll
    for (int mt = 0; mt < 9; mt++)
      a[mt] = *(const bf16x8*)(cur + (mstrip + mt * 16 + l15) * 32 + qp_c * 8);
#pragma unroll
    for (int nt = 0; nt < 4; nt++)
      b[nt] = *(const bf16x8*)(cur + ABUF + (nstrip + nt * 16 + l15) * 32 + qp_c * 8);
#pragma unroll
    for (int mt = 0; mt < 9; mt++)
#pragma unroll
      for (int nt = 0; nt < 4; nt++)
        acc[mt][nt] = __builtin_amdgcn_mfma_f32_16x16x32_bf16(a[mt], b[nt], acc[mt][nt], 0, 0, 0);
  }

  // epilogue: wave strip = 144 rows = 4 bi; max over 36 j-rows each, + residual
#pragma unroll
  for (int nt = 0; nt < 4; nt++) {
#pragma unroll
    for (int h = 0; h < 4; h++) {
      float m1 = -3.0e38f;
#pragma unroll
      for (int mt = 0; mt < 9; mt++)
#pragma unroll
        for (int r = 0; r < 4; r++) {
          int row = mt * 16 + qv * 4 + r;   // within strip, 0..143
          if (row >= h * NREG && row < h * NREG + NREG) m1 = fmaxf(m1, acc[mt][nt][r]);
        }
      m1 = fmaxf(m1, __shfl_xor(m1, 16, 64));
      m1 = fmaxf(m1, __shfl_xor(m1, 32, 64));
      if (lane < 16) {
        int bi = go * 8 + (wave >> 1) * 4 + h;
        long o = (long)bi * DD + d0 + nstrip + nt * 16 + lane;
        out[o] = m1 + mm[o];
      }
    }
  }
}

// ---------------- launcher ----------------
extern "C" void kernel_launch(void* const* d_in, const int* in_sizes, int n_in,
                              void* d_out, int out_size, void* d_ws, size_t ws_size,
                              hipStream_t stream) {
  const float* mm     = (const float*)d_in[0];
  const float* coords = (const float*)d_in[1];
  const float* U_feat = (const float*)d_in[2];
  const float* V_feat = (const float*)d_in[3];
  const float* P_feat = (const float*)d_in[4];
  const float* U_coord= (const float*)d_in[5];
  const float* V_coord= (const float*)d_in[6];
  const float* P_coord= (const float*)d_in[7];
  float* out = (float*)d_out;

  char* ws = (char*)d_ws;
  bf16* z   = (bf16*)(ws + 0);                 //  84,934,656 B  [kc][41472][32]
  bf16* PTt = (bf16*)(ws + 84934656);          //   4,194,304 B  [kc][2048][32]
  bf16* mmb = (bf16*)(ws + 89128960);          //   4,718,592 B
  bf16* UT  = (bf16*)(ws + 93847552);          //   2,097,152 B  [512][2048]
  bf16* VT  = (bf16*)(ws + 95944704);          //   2,097,152 B
  float* uf = (float*)(ws + 98041856);         //   2,359,296 B
  float* vf = (float*)(ws + 100401152);
  float* uc = (float*)(ws + 102760448);
  float* vc = (float*)(ws + 105119744);        // end 107,479,040

  k_cvt_mm<<<dim3(2304), dim3(256), 0, stream>>>((const float4*)mm, (bf16x4*)mmb);
  k_transpose_uv<<<dim3(16, 64, 2), dim3(32, 8), 0, stream>>>(U_feat, V_feat, UT, VT);
  k_transpose_pt<<<dim3(64, 16, 2), dim3(32, 8), 0, stream>>>(P_coord, P_feat, PTt);
  k_uvcoord<<<dim3(BI), dim3(256), 0, stream>>>(coords, U_coord, V_coord, uc, vc);
  k_gemm_uv<<<dim3(8, 18, 2), dim3(256), 0, stream>>>(mmb, UT, VT, uf, vf);
  k_build_z<<<dim3(8, 32), dim3(256), 0, stream>>>(uc, vc, uf, vf, z);
  k_main<<<dim3(2304), dim3(256), 0, stream>>>(z, PTt, mm, out);
}